// Round 1
// 838.528 us; speedup vs baseline: 1.0697x; 1.0697x over previous
//
#include <hip/hip_runtime.h>
#include <cstdint>
#include <cstddef>

// ---------------- open-addressing hash params ----------------
#define OA_LOG 21
static constexpr unsigned OA_SLOTS = 1u << OA_LOG;   // 2M slots x 8B = 16 MB, load ~0.5
static constexpr unsigned OA_MASK  = OA_SLOTS - 1;
static constexpr unsigned HASH_MUL = 2654435761u;    // Knuth multiplicative

typedef __attribute__((ext_vector_type(8))) short short8;   // 8 bf16 (4 VGPRs)
typedef __attribute__((ext_vector_type(4))) float floatx4;  // MFMA C/D

union U4S8 { uint4 u; short8 s; };

__device__ inline unsigned bf16rn(float x) {                // RNE f32->bf16
    unsigned u = __float_as_uint(x);
    return (u + 0x7FFFu + ((u >> 16) & 1u)) >> 16;
}
__device__ inline unsigned pk2(float a, float b) {
    return bf16rn(a) | (bf16rn(b) << 16);
}

// ---- pack W (128x64 f32, row-major) into 16 MFMA B-fragments of bf16 ----
// frag (s,t): B[k=32s+8q+j][n=16t+(lane&15)], j=0..7, q=lane>>4.
__global__ void wpack_kernel(const float* __restrict__ W, uint4* __restrict__ wsW) {
    const int lane = threadIdx.x;   // 64 threads
    const int n = lane & 15, q = lane >> 4;
    for (int s = 0; s < 4; ++s)
        for (int t = 0; t < 4; ++t) {
            unsigned dw[4];
#pragma unroll
            for (int jj = 0; jj < 4; ++jj) {
                float a = W[(32 * s + 8 * q + 2 * jj) * 64 + 16 * t + n];
                float b = W[(32 * s + 8 * q + 2 * jj + 1) * 64 + 16 * t + n];
                dw[jj] = pk2(a, b);
            }
            wsW[(s * 4 + t) * 64 + lane] = make_uint4(dw[0], dw[1], dw[2], dw[3]);
        }
}

// ---- CSR build: histogram -> scan -> scatter (unchanged) ----
__global__ void hist_kernel(const int* __restrict__ edst, int* __restrict__ cnt, int E) {
    int e = blockIdx.x * blockDim.x + threadIdx.x;
    if (e < E) atomicAdd(&cnt[edst[e]], 1);
}

__global__ void scan_kernel(int* __restrict__ cnt, int* __restrict__ off, int NN, int E) {
    __shared__ int sd[1024];
    const int t = threadIdx.x;
    const int chunk = (NN + 1023) >> 10;
    const int lo = t * chunk, hi = min(lo + chunk, NN);
    int local = 0;
    for (int i = lo; i < hi; ++i) local += cnt[i];
    sd[t] = local;
    __syncthreads();
    for (int s = 1; s < 1024; s <<= 1) {
        int v = (t >= s) ? sd[t - s] : 0;
        __syncthreads();
        sd[t] += v;
        __syncthreads();
    }
    int run = sd[t] - local;  // exclusive base
    for (int i = lo; i < hi; ++i) {
        int c = cnt[i];
        off[i] = run;
        cnt[i] = run;   // cursor
        run += c;
    }
    if (t == 0) off[NN] = E;
}

__global__ void scatter_kernel(const int* __restrict__ edst, int* __restrict__ cursor,
                               int* __restrict__ csr, int E) {
    int e = blockIdx.x * blockDim.x + threadIdx.x;
    if (e >= E) return;
    int slot = atomicAdd(&cursor[edst[e]], 1);
    csr[slot] = e;
}

// ---- agg via CSR: one wave per node, lane = column (unchanged) ----
__global__ __launch_bounds__(256)
void agg_csr_kernel(const float* __restrict__ feat, const int* __restrict__ csr,
                    const int* __restrict__ off, float* __restrict__ agg, int NN) {
    const int wid = (blockIdx.x * blockDim.x + threadIdx.x) >> 6;
    const int lane = threadIdx.x & 63;
    if (wid >= NN) return;
    const int i0 = off[wid], i1 = off[wid + 1];
    float acc = 0.f;
    int i = i0;
    for (; i + 4 <= i1; i += 4) {
        int c0 = csr[i], c1 = csr[i + 1], c2 = csr[i + 2], c3 = csr[i + 3];
        float a0 = feat[((long long)c0 << 6) + lane];
        float a1 = feat[((long long)c1 << 6) + lane];
        float a2 = feat[((long long)c2 << 6) + lane];
        float a3 = feat[((long long)c3 << 6) + lane];
        acc += (a0 + a1) + (a2 + a3);
    }
    for (; i < i1; ++i) acc += feat[((long long)csr[i] << 6) + lane];
    agg[((long long)wid << 6) + lane] = acc;
}

// ---- open-addressed build: slot = {key(lo32), edge_idx(hi32)}, linear probe ----
__global__ void build_oa_kernel(const int* __restrict__ esrc,
                                const int* __restrict__ edst,
                                unsigned long long* __restrict__ tbl,
                                int E, unsigned NN) {
    int e = blockIdx.x * blockDim.x + threadIdx.x;
    if (e >= E) return;
    unsigned k = (unsigned)esrc[e] * NN + (unsigned)edst[e];   // < NN*NN < 2^31, never 0xFFFFFFFF
    unsigned long long mine = ((unsigned long long)(unsigned)e << 32) | (unsigned long long)k;
    unsigned s = (k * HASH_MUL) >> (32 - OA_LOG);
    const unsigned long long EMPTY = ~0ull;
    while (atomicCAS(&tbl[s], EMPTY, mine) != EMPTY)
        s = (s + 1) & OA_MASK;
}

// ---- race-free reverse resolution from the FINAL table (read-only):
// revid[e] = idx of unique edge with key == rev(e); -1 if group size != 1
// (0 or >=2) -> fused takes slow probe path (which also yields 0 for empty).
__global__ void mark_rev_kernel(const int* __restrict__ esrc,
                                const int* __restrict__ edst,
                                const unsigned long long* __restrict__ tbl,
                                int* __restrict__ revid,
                                int E, unsigned NN) {
    int e = blockIdx.x * blockDim.x + threadIdx.x;
    if (e >= E) return;
    unsigned rk = (unsigned)edst[e] * NN + (unsigned)esrc[e];
    unsigned s = (rk * HASH_MUL) >> (32 - OA_LOG);
    int cnt = 0, idx = -1;
    while (true) {
        unsigned long long v = tbl[s];
        if ((unsigned)v == 0xFFFFFFFFu) break;        // empty -> end of cluster
        if ((unsigned)v == rk) { ++cnt; idx = (int)(v >> 32); }
        s = (s + 1) & OA_MASK;
    }
    revid[e] = (cnt == 1) ? idx : -1;
}

// ---- fused: h = [feat, agg[src]-revsum] (bf16, LDS) ; out = relu(h@W + b) via MFMA ----
// Paired block layout (E%64==0): block g covers edges [32g,32g+32) and its
// mirror [E/2+32g, E/2+32g+32), so each feat row loaded as "self" is the
// reverse row of the partner edge in the SAME block -> L1-shared, feat read 1x.
__global__ __launch_bounds__(256, 2)
void fused_kernel(const float* __restrict__ feat,
                  const int* __restrict__ esrc,
                  const int* __restrict__ edst,
                  const float* __restrict__ agg,
                  const unsigned long long* __restrict__ tbl,
                  const int* __restrict__ revid,
                  const uint4* __restrict__ wsW,
                  const float* __restrict__ bias,
                  float* __restrict__ out,
                  int E, unsigned NN) {
    // 64 edge rows x 128 bf16 cols, padded to 68 dwords/row
    __shared__ unsigned lds_h[64 * 68];
    const int tid = threadIdx.x;
    const int lane = tid & 63;
    const int n = lane & 15;
    const int q = lane >> 4;
    const int g = blockIdx.x;
    const long long H = (long long)(E >> 1);
    const bool paired = (E & 63) == 0;

    // W fragments: 16 x uint4 coalesced loads (L2-hot), latency hidden by phase 1
    short8 wf[4][4];
#pragma unroll
    for (int s = 0; s < 4; ++s)
#pragma unroll
        for (int t = 0; t < 4; ++t) {
            U4S8 cvt;
            cvt.u = wsW[(s * 4 + t) * 64 + lane];
            wf[s][t] = cvt.s;
        }
    float bv[4];
#pragma unroll
    for (int t = 0; t < 4; ++t) bv[t] = bias[16 * t + n];

    // ---- phase 1: 4 threads/edge, 16 cols each ----
    const int el = tid >> 2;     // LDS row 0..63
    const int p = tid & 3;
    long long e;
    if (paired) e = (long long)g * 32 + (el & 31) + (long long)(el >> 5) * H;
    else        e = (long long)g * 64 + el;

    float4 f0, f1, f2, f3, m0, m1, m2, m3;
    if (e < (long long)E) {
        const float4* fp = (const float4*)(feat + (e << 6) + 16 * p);
        f0 = fp[0]; f1 = fp[1]; f2 = fp[2]; f3 = fp[3];
        const int s_ = esrc[e], d_ = edst[e];
        const float4* ap = (const float4*)(agg + ((long long)s_ << 6) + 16 * p);
        m0 = ap[0]; m1 = ap[1]; m2 = ap[2]; m3 = ap[3];

        const int rid = revid[e];
        float4 r0, r1, r2, r3;
        if (rid >= 0) {
            // fast path (~98.4%): unique reverse edge; row is L1-hot (partner
            // thread-group in this block loads it as its self row)
            const float4* rp = (const float4*)(feat + ((long long)rid << 6) + 16 * p);
            r0 = rp[0]; r1 = rp[1]; r2 = rp[2]; r3 = rp[3];
        } else {
            // slow path: linear-probe cluster, sum ALL matches (multi-edges);
            // also correct (sum=0) when no reverse edge exists.
            r0 = r1 = r2 = r3 = make_float4(0.f, 0.f, 0.f, 0.f);
            const unsigned rk = (unsigned)d_ * NN + (unsigned)s_;
            unsigned slot = (rk * HASH_MUL) >> (32 - OA_LOG);
            while (true) {
                unsigned long long v = tbl[slot];
                if ((unsigned)v == 0xFFFFFFFFu) break;
                if ((unsigned)v == rk) {
                    const float4* rp =
                        (const float4*)(feat + ((long long)(v >> 32) << 6) + 16 * p);
                    float4 a0 = rp[0], a1 = rp[1], a2 = rp[2], a3 = rp[3];
                    r0.x += a0.x; r0.y += a0.y; r0.z += a0.z; r0.w += a0.w;
                    r1.x += a1.x; r1.y += a1.y; r1.z += a1.z; r1.w += a1.w;
                    r2.x += a2.x; r2.y += a2.y; r2.z += a2.z; r2.w += a2.w;
                    r3.x += a3.x; r3.y += a3.y; r3.z += a3.z; r3.w += a3.w;
                }
                slot = (slot + 1) & OA_MASK;
            }
        }
        m0.x -= r0.x; m0.y -= r0.y; m0.z -= r0.z; m0.w -= r0.w;
        m1.x -= r1.x; m1.y -= r1.y; m1.z -= r1.z; m1.w -= r1.w;
        m2.x -= r2.x; m2.y -= r2.y; m2.z -= r2.z; m2.w -= r2.w;
        m3.x -= r3.x; m3.y -= r3.y; m3.z -= r3.z; m3.w -= r3.w;
    } else {
        f0 = f1 = f2 = f3 = make_float4(0.f, 0.f, 0.f, 0.f);
        m0 = m1 = m2 = m3 = make_float4(0.f, 0.f, 0.f, 0.f);
    }
    unsigned* row = &lds_h[el * 68];
    *(uint4*)(row + 8 * p) =
        make_uint4(pk2(f0.x, f0.y), pk2(f0.z, f0.w), pk2(f1.x, f1.y), pk2(f1.z, f1.w));
    *(uint4*)(row + 8 * p + 4) =
        make_uint4(pk2(f2.x, f2.y), pk2(f2.z, f2.w), pk2(f3.x, f3.y), pk2(f3.z, f3.w));
    *(uint4*)(row + 32 + 8 * p) =
        make_uint4(pk2(m0.x, m0.y), pk2(m0.z, m0.w), pk2(m1.x, m1.y), pk2(m1.z, m1.w));
    *(uint4*)(row + 32 + 8 * p + 4) =
        make_uint4(pk2(m2.x, m2.y), pk2(m2.z, m2.w), pk2(m3.x, m3.y), pk2(m3.z, m3.w));
    __syncthreads();

    // ---- phase 2: wave w computes LDS rows [16w, 16w+16) x all 64 cols ----
    const int w = tid >> 6;
    floatx4 acc[4];
#pragma unroll
    for (int t = 0; t < 4; ++t) acc[t] = (floatx4){0.f, 0.f, 0.f, 0.f};
#pragma unroll
    for (int s = 0; s < 4; ++s) {
        U4S8 a;
        a.u = *(const uint4*)&lds_h[(16 * w + n) * 68 + 16 * s + 4 * q];
#pragma unroll
        for (int t = 0; t < 4; ++t)
            acc[t] = __builtin_amdgcn_mfma_f32_16x16x32_bf16(a.s, wf[s][t], acc[t], 0, 0, 0);
    }

    // ---- epilogue: C layout col=lane&15, row=4q+reg; map LDS row -> edge ----
#pragma unroll
    for (int r = 0; r < 4; ++r) {
        const int rowi = 16 * w + 4 * q + r;
        long long ee;
        if (paired) ee = (long long)g * 32 + (rowi & 31) + (long long)(rowi >> 5) * H;
        else        ee = (long long)g * 64 + rowi;
        if (ee < (long long)E) {
#pragma unroll
            for (int t = 0; t < 4; ++t) {
                float v = acc[t][r] + bv[t];
                out[(ee << 6) + 16 * t + n] = v > 0.f ? v : 0.f;
            }
        }
    }
}

extern "C" void kernel_launch(void* const* d_in, const int* in_sizes, int n_in,
                              void* d_out, int out_size, void* d_ws, size_t ws_size,
                              hipStream_t stream) {
    const float* feat = (const float*)d_in[0];
    const int*   esrc = (const int*)d_in[1];
    const int*   edst = (const int*)d_in[2];
    const float* W    = (const float*)d_in[5];
    const float* bias = (const float*)d_in[6];
    float* out = (float*)d_out;

    const int E  = in_sizes[1];
    const int NN = in_sizes[3];

    // workspace layout (16B aligned)
    char* ws = (char*)d_ws;
    size_t o = 0;
    auto alloc = [&](size_t bytes) { void* p = ws + o; o = (o + bytes + 15) & ~(size_t)15; return p; };
    float* agg   = (float*)alloc((size_t)NN * 64 * sizeof(float));              // 10.24 MB
    int*   cnt   = (int*)alloc((size_t)NN * sizeof(int));                       // 160 KB (also cursor)
    int*   off   = (int*)alloc((size_t)(NN + 1) * sizeof(int));                 // 160 KB
    int*   csr   = (int*)alloc((size_t)E * sizeof(int));                        // 4 MB
    unsigned long long* tbl = (unsigned long long*)alloc((size_t)OA_SLOTS * 8); // 16 MB
    int*   revid = (int*)alloc((size_t)E * sizeof(int));                        // 4 MB
    uint4* wsW   = (uint4*)alloc((size_t)16 * 64 * sizeof(uint4));              // 16 KB

    hipMemsetAsync(cnt, 0, (size_t)NN * sizeof(int), stream);
    hipMemsetAsync(tbl, 0xFF, (size_t)OA_SLOTS * 8, stream);

    const int eb = (E + 255) / 256;
    wpack_kernel<<<1, 64, 0, stream>>>(W, wsW);
    hist_kernel<<<eb, 256, 0, stream>>>(edst, cnt, E);
    scan_kernel<<<1, 1024, 0, stream>>>(cnt, off, NN, E);
    scatter_kernel<<<eb, 256, 0, stream>>>(edst, cnt, csr, E);
    build_oa_kernel<<<eb, 256, 0, stream>>>(esrc, edst, tbl, E, (unsigned)NN);
    mark_rev_kernel<<<eb, 256, 0, stream>>>(esrc, edst, tbl, revid, E, (unsigned)NN);
    agg_csr_kernel<<<(NN + 3) / 4, 256, 0, stream>>>(feat, csr, off, agg, NN);
    fused_kernel<<<(E + 63) / 64, 256, 0, stream>>>(
        feat, esrc, edst, agg, tbl, revid, wsW, bias, out, E, (unsigned)NN);
}